// Round 7
// baseline (81.508 us; speedup 1.0000x reference)
//
#include <hip/hip_runtime.h>
#include <math.h>

// Problem constants (match reference)
#define NXC 1024
#define NYC 1024
#define DC  128
#define NCM1 4
#define NBLK 256   // 16x16 tiles of 64x64

// ws float offsets
#define WS_STILE 0          // 256 blocks * 4096 floats (64x64 f32 s-tiles) = 4 MB
#define WS_ROWP  1048576    // float2[1024][16] (m,l) row partials -> 32768 floats
#define WS_COLP  1081344    // float2[1024][16] (m,l) col partials -> 32768 floats
#define WS_PART  1114112    // float2[256] (S0,S1) block partials  ->   512 floats
#define WS_CNT   1114624    // 1 int (completion counter; init by kernel A)

typedef _Float16 half2v __attribute__((ext_vector_type(2)));
union H2U { half2v h; unsigned u; };
union F2U { float2 f; unsigned long long u; };

#if defined(__has_builtin)
#if __has_builtin(__builtin_amdgcn_fdot2)
#define HAVE_FDOT2 1
#endif
#endif

// |xa - ya| summed into f32 acc, 8 halves (one 16B chunk) at a time.
__device__ __forceinline__ float absdiff_dot(uint4 xa, uint4 ya, float acc)
{
    const unsigned* xu = (const unsigned*)&xa;
    const unsigned* yu = (const unsigned*)&ya;
    half2v one; one.x = (_Float16)1.f; one.y = (_Float16)1.f;
    #pragma unroll
    for (int q = 0; q < 4; ++q) {
        H2U x, y, d;
        x.u = xu[q]; y.u = yu[q];
        d.h = x.h - y.h;              // v_pk_add_f16 (neg)
        d.u &= 0x7FFF7FFFu;           // packed abs
#ifdef HAVE_FDOT2
        acc = __builtin_amdgcn_fdot2(d.h, one, acc, false);  // v_dot2_f32_f16
#else
        acc += (float)d.h.x + (float)d.h.y;
#endif
    }
    return acc;
}

// -------------------------------------------------------------------------
// Kernel A: 256 blocks (64x64 tile each) x 512 threads. fp16 staged LDS,
// 2x4 micro-tile per thread. Outputs: s-tile (f32, thread-contiguous layout
// shared with kernel B), per-tile row/col partials. Also inits the counter
// kernel B's last-block pattern needs (stream order guarantees visibility).
// -------------------------------------------------------------------------
__global__ __launch_bounds__(512, 2) void distance_kernel(
    const float* __restrict__ zx, const float* __restrict__ zy,
    float* __restrict__ ws)
{
    __shared__ __align__(16) _Float16 xs[64 * 128];
    __shared__ __align__(16) _Float16 ys[64 * 128];
    __shared__ float cpm[32][64], cpl[32][64];

    float* stile = ws + WS_STILE;
    float* rowp  = ws + WS_ROWP;
    float* colp  = ws + WS_COLP;

    const int t  = threadIdx.x;
    const int bx = blockIdx.x & 15;   // col-tile index
    const int by = blockIdx.x >> 4;   // row-tile index
    const int x0 = by * 64;
    const int y0 = bx * 64;

    if (blockIdx.x == 0 && t == 0)
        ((int*)ws)[WS_CNT] = 0;       // plain store; visible to kernel B via stream order

    // ---- stage 64x128 of zx, zy into LDS as fp16 (RNE casts) ----
    #pragma unroll
    for (int k = 0; k < 2; ++k) {
        int idx = t + k * 512;        // half8-chunk index: 64 rows x 16 chunks
        int r   = idx >> 4;
        int j   = idx & 15;
        int off = r * 128 + 8 * (j ^ ((r >> 2) & 7));

        const float4* gx = (const float4*)(zx + (size_t)(x0 + r) * DC + 8 * j);
        float4 xv0 = gx[0], xv1 = gx[1];
        const float4* gy = (const float4*)(zy + (size_t)(y0 + r) * DC + 8 * j);
        float4 yv0 = gy[0], yv1 = gy[1];

        uint4 hx, hy;
        {
            H2U a, b, c, d;
            a.h.x = (_Float16)xv0.x; a.h.y = (_Float16)xv0.y;
            b.h.x = (_Float16)xv0.z; b.h.y = (_Float16)xv0.w;
            c.h.x = (_Float16)xv1.x; c.h.y = (_Float16)xv1.y;
            d.h.x = (_Float16)xv1.z; d.h.y = (_Float16)xv1.w;
            hx.x = a.u; hx.y = b.u; hx.z = c.u; hx.w = d.u;
            a.h.x = (_Float16)yv0.x; a.h.y = (_Float16)yv0.y;
            b.h.x = (_Float16)yv0.z; b.h.y = (_Float16)yv0.w;
            c.h.x = (_Float16)yv1.x; c.h.y = (_Float16)yv1.y;
            d.h.x = (_Float16)yv1.z; d.h.y = (_Float16)yv1.w;
            hy.x = a.u; hy.y = b.u; hy.z = c.u; hy.w = d.u;
        }
        *(uint4*)(xs + off) = hx;
        *(uint4*)(ys + off) = hy;
    }
    __syncthreads();

    const int tx = t & 15;            // 4 cols each
    const int ty = t >> 4;            // 0..31, 2 rows each
    const int xswz = (ty >> 1) & 7;
    const int yswz = tx & 7;

    const _Float16* xb = xs + (2 * ty) * 128;
    const _Float16* yb = ys + (4 * tx) * 128;

    // ---- 2x4 micro-tile L1 distances, distance-1 prefetch (branchless) ----
    float acc[2][4];
    #pragma unroll
    for (int i = 0; i < 2; ++i)
        #pragma unroll
        for (int j = 0; j < 4; ++j) acc[i][j] = 0.f;

    uint4 xc0 = *(const uint4*)(xb +       8 * (0 ^ xswz));
    uint4 xc1 = *(const uint4*)(xb + 128 + 8 * (0 ^ xswz));
    uint4 yc0 = *(const uint4*)(yb +       8 * (0 ^ yswz));
    uint4 yc1 = *(const uint4*)(yb + 128 + 8 * (0 ^ yswz));
    uint4 yc2 = *(const uint4*)(yb + 256 + 8 * (0 ^ yswz));
    uint4 yc3 = *(const uint4*)(yb + 384 + 8 * (0 ^ yswz));

    #pragma unroll 4
    for (int j = 0; j < 16; ++j) {
        uint4 xa0 = xc0, xa1 = xc1, ya0 = yc0, ya1 = yc1, ya2 = yc2, ya3 = yc3;
        const int jn = (j + 1) & 15;
        xc0 = *(const uint4*)(xb +       8 * (jn ^ xswz));
        xc1 = *(const uint4*)(xb + 128 + 8 * (jn ^ xswz));
        yc0 = *(const uint4*)(yb +       8 * (jn ^ yswz));
        yc1 = *(const uint4*)(yb + 128 + 8 * (jn ^ yswz));
        yc2 = *(const uint4*)(yb + 256 + 8 * (jn ^ yswz));
        yc3 = *(const uint4*)(yb + 384 + 8 * (jn ^ yswz));

        acc[0][0] = absdiff_dot(xa0, ya0, acc[0][0]);
        acc[0][1] = absdiff_dot(xa0, ya1, acc[0][1]);
        acc[0][2] = absdiff_dot(xa0, ya2, acc[0][2]);
        acc[0][3] = absdiff_dot(xa0, ya3, acc[0][3]);
        acc[1][0] = absdiff_dot(xa1, ya0, acc[1][0]);
        acc[1][1] = absdiff_dot(xa1, ya1, acc[1][1]);
        acc[1][2] = absdiff_dot(xa1, ya2, acc[1][2]);
        acc[1][3] = absdiff_dot(xa1, ya3, acc[1][3]);
    }

    float sv[2][4];
    #pragma unroll
    for (int i = 0; i < 2; ++i)
        #pragma unroll
        for (int j = 0; j < 4; ++j) sv[i][j] = -acc[i][j];

    // ---- store s-tile (thread-contiguous, reread identically by kernel B) ----
    {
        float* sb = stile + (size_t)blockIdx.x * 4096 + t * 8;
        *(float4*)(sb)     = make_float4(sv[0][0], sv[0][1], sv[0][2], sv[0][3]);
        *(float4*)(sb + 4) = make_float4(sv[1][0], sv[1][1], sv[1][2], sv[1][3]);
    }

    // ---- per-tile ROW partials (merge across tx, in-wave) ----
    #pragma unroll
    for (int i = 0; i < 2; ++i) {
        float m = fmaxf(fmaxf(sv[i][0], sv[i][1]), fmaxf(sv[i][2], sv[i][3]));
        float l = __expf(sv[i][0] - m) + __expf(sv[i][1] - m)
                + __expf(sv[i][2] - m) + __expf(sv[i][3] - m);
        #pragma unroll
        for (int off = 1; off < 16; off <<= 1) {
            float mo = __shfl_xor(m, off, 64);
            float lo = __shfl_xor(l, off, 64);
            float nm = fmaxf(m, mo);
            l = l * __expf(m - nm) + lo * __expf(mo - nm);
            m = nm;
        }
        if (tx == 0)
            *(float2*)(rowp + 2 * ((size_t)(x0 + 2 * ty + i) * 16 + bx)) = make_float2(m, l);
    }

    // ---- per-tile COL partials (merge across ty via LDS) ----
    #pragma unroll
    for (int j = 0; j < 4; ++j) {
        float m = fmaxf(sv[0][j], sv[1][j]);
        float l = __expf(sv[0][j] - m) + __expf(sv[1][j] - m);
        cpm[ty][4 * tx + j] = m;
        cpl[ty][4 * tx + j] = l;
    }
    __syncthreads();
    if (t < 64) {
        float m = cpm[0][t], l = cpl[0][t];
        #pragma unroll 8
        for (int k = 1; k < 32; ++k) {
            float mo = cpm[k][t], lo = cpl[k][t];
            float nm = fmaxf(m, mo);
            l = l * __expf(m - nm) + lo * __expf(mo - nm);
            m = nm;
        }
        *(float2*)(colp + 2 * ((size_t)(y0 + t) * 16 + by)) = make_float2(m, l);
    }
}

// -------------------------------------------------------------------------
// Kernel B: same grid/tile mapping. Combine the 16 row/col partials for this
// tile (8 lanes/row, coalesced float4 + 3 shuffle merges), reload the s-tile
// (prefetched), accumulate S0/S1, write one partial per block. The LAST
// block to finish (device-scope counter) sums all 256 partials and writes
// the logits — deterministic result regardless of which block is last.
// -------------------------------------------------------------------------
__global__ __launch_bounds__(512, 2) void reduce_kernel(
    float* __restrict__ ws,
    const float* __restrict__ theta, const float* __restrict__ beta,
    float* __restrict__ out)
{
    __shared__ float rm_s[64], rl_s[64], cm_s[64], cl_s[64];
    __shared__ float red0[8], red1[8];
    __shared__ int last_s;

    const float* stile = ws + WS_STILE;
    const float4* rowp4 = (const float4*)(ws + WS_ROWP);  // [row][8] of (m0,l0,m1,l1)
    const float4* colp4 = (const float4*)(ws + WS_COLP);
    float* part = ws + WS_PART;
    int*   cnt  = (int*)ws + WS_CNT;

    const int t  = threadIdx.x;
    const int bx = blockIdx.x & 15;
    const int by = blockIdx.x >> 4;
    const int x0 = by * 64;
    const int y0 = bx * 64;

    // prefetch s-tile (consumed after the combine; loads overlap it)
    const float* sb = stile + (size_t)blockIdx.x * 4096 + t * 8;
    float4 s0 = ((const float4*)sb)[0];
    float4 s1 = ((const float4*)sb)[1];

    // ---- combine 16 partials per row: 8 lanes/row, float4 + 3 shuffles ----
    const int item  = t >> 3;        // 0..63 (row or col index within tile)
    const int chunk = t & 7;         // which float4 (2 partials)
    {
        float4 q = rowp4[(size_t)(x0 + item) * 8 + chunk];
        float m = fmaxf(q.x, q.z);
        float l = q.y * __expf(q.x - m) + q.w * __expf(q.z - m);
        #pragma unroll
        for (int off = 1; off < 8; off <<= 1) {
            float mo = __shfl_xor(m, off, 64);
            float lo = __shfl_xor(l, off, 64);
            float nm = fmaxf(m, mo);
            l = l * __expf(m - nm) + lo * __expf(mo - nm);
            m = nm;
        }
        if (chunk == 0) { rm_s[item] = m; rl_s[item] = 1.f / l; }
    }
    {
        float4 q = colp4[(size_t)(y0 + item) * 8 + chunk];
        float m = fmaxf(q.x, q.z);
        float l = q.y * __expf(q.x - m) + q.w * __expf(q.z - m);
        #pragma unroll
        for (int off = 1; off < 8; off <<= 1) {
            float mo = __shfl_xor(m, off, 64);
            float lo = __shfl_xor(l, off, 64);
            float nm = fmaxf(m, mo);
            l = l * __expf(m - nm) + lo * __expf(mo - nm);
            m = nm;
        }
        if (chunk == 0) { cm_s[item] = m; cl_s[item] = 1.f / l; }
    }
    __syncthreads();

    const int tx = t & 15;
    const int ty = t >> 4;
    float sv[2][4] = {{s0.x, s0.y, s0.z, s0.w}, {s1.x, s1.y, s1.z, s1.w}};

    float S0 = 0.f, S1 = 0.f;
    #pragma unroll
    for (int i = 0; i < 2; ++i) {
        const float rm = rm_s[2 * ty + i];
        const float rl = rl_s[2 * ty + i];
        #pragma unroll
        for (int j = 0; j < 4; ++j) {
            const float cm = cm_s[4 * tx + j];
            const float cl = cl_s[4 * tx + j];
            float s = sv[i][j];
            float a = __expf(s - rm) * rl;
            float b = __expf(s - cm) * cl;
            float w = a + b - a * b;
            S0 += w;
            S1 += w * s;
        }
    }
    #pragma unroll
    for (int off = 32; off; off >>= 1) {
        S0 += __shfl_xor(S0, off, 64);
        S1 += __shfl_xor(S1, off, 64);
    }
    {
        const int wave = t >> 6, lane = t & 63;
        if (lane == 0) { red0[wave] = S0; red1[wave] = S1; }
    }
    __syncthreads();
    if (t == 0) {
        float t0 = 0.f, t1 = 0.f;
        #pragma unroll
        for (int w = 0; w < 8; ++w) { t0 += red0[w]; t1 += red1[w]; }
        *(float2*)(part + 2 * blockIdx.x) = make_float2(t0, t1);
        __threadfence();   // flush partial to device scope
        int old = __hip_atomic_fetch_add(cnt, 1, __ATOMIC_ACQ_REL, __HIP_MEMORY_SCOPE_AGENT);
        last_s = (old == NBLK - 1);
    }
    __syncthreads();

    // ---- last block: sum 256 partials (fixed order -> deterministic) ----
    if (last_s) {
        float S0f = 0.f, S1f = 0.f;
        if (t < NBLK) {
            F2U u;
            u.u = __hip_atomic_load((const unsigned long long*)(part + 2 * t),
                                    __ATOMIC_RELAXED, __HIP_MEMORY_SCOPE_AGENT);
            S0f = u.f.x; S1f = u.f.y;
        }
        #pragma unroll
        for (int off = 32; off; off >>= 1) {
            S0f += __shfl_xor(S0f, off, 64);
            S1f += __shfl_xor(S1f, off, 64);
        }
        {
            const int wave = t >> 6, lane = t & 63;
            if (lane == 0) { red0[wave] = S0f; red1[wave] = S1f; }
        }
        __syncthreads();
        if (t < NCM1) {
            float t0 = red0[0] + red0[1] + red0[2] + red0[3];
            float t1 = red1[0] + red1[1] + red1[2] + red1[3];
            float c = t1 / t0;
            out[t] = c * theta[t] + beta[t];
        }
    }
}

// -------------------------------------------------------------------------
extern "C" void kernel_launch(void* const* d_in, const int* in_sizes, int n_in,
                              void* d_out, int out_size, void* d_ws, size_t ws_size,
                              hipStream_t stream)
{
    const float* zx    = (const float*)d_in[0];
    const float* zy    = (const float*)d_in[1];
    const float* theta = (const float*)d_in[2];
    const float* beta  = (const float*)d_in[3];
    float* out = (float*)d_out;
    float* ws  = (float*)d_ws;

    distance_kernel<<<NBLK, 512, 0, stream>>>(zx, zy, ws);
    reduce_kernel<<<NBLK, 512, 0, stream>>>(ws, theta, beta, out);
}

// Round 8
// 76.670 us; speedup vs baseline: 1.0631x; 1.0631x over previous
//
#include <hip/hip_runtime.h>
#include <math.h>

// Problem constants (match reference)
#define NXC 1024
#define NYC 1024
#define DC  128
#define NCM1 4
#define NTILE 256   // 16x16 tiles of 64x64
#define NBLKA 512   // kernel A: 2 blocks per tile (64x32 half-tiles), 2 blocks/CU

// ws float offsets
#define WS_STILE 0          // 256 tiles * 4096 floats (64x64 f32 s-tiles) = 4 MB
#define WS_ROWP  1048576    // float2[1024][32] (m,l) row partials -> 65536 floats
#define WS_COLP  1114112    // float2[1024][16] (m,l) col partials -> 32768 floats
#define WS_PART  1146880    // float2[256] (S0,S1) tile partials   ->   512 floats

typedef _Float16 half2v __attribute__((ext_vector_type(2)));
union H2U { half2v h; unsigned u; };

#if defined(__has_builtin)
#if __has_builtin(__builtin_amdgcn_fdot2)
#define HAVE_FDOT2 1
#endif
#endif

// |xa - ya| summed into f32 acc, 8 halves (one 16B chunk) at a time.
__device__ __forceinline__ float absdiff_dot(uint4 xa, uint4 ya, float acc)
{
    const unsigned* xu = (const unsigned*)&xa;
    const unsigned* yu = (const unsigned*)&ya;
    half2v one; one.x = (_Float16)1.f; one.y = (_Float16)1.f;
    #pragma unroll
    for (int q = 0; q < 4; ++q) {
        H2U x, y, d;
        x.u = xu[q]; y.u = yu[q];
        d.h = x.h - y.h;              // v_pk_add_f16 (neg)
        d.u &= 0x7FFF7FFFu;           // packed abs
#ifdef HAVE_FDOT2
        acc = __builtin_amdgcn_fdot2(d.h, one, acc, false);  // v_dot2_f32_f16
#else
        acc += (float)d.h.x + (float)d.h.y;
#endif
    }
    return acc;
}

// -------------------------------------------------------------------------
// Kernel A: 512 blocks x 256 threads, 2 blocks/CU. Block = 64x32 half-tile
// (rows x0..x0+63, cols y0..y0+31). fp16 staged LDS (~32 KB/block so two
// blocks co-reside: one block's staging overlaps the other's compute).
// Outputs: s half-tile (f32, thread-contiguous layout shared with kernel B),
// per-half-tile row partials (32/row), per-tile col partials (16/col).
// Plain stores only; kernel boundary is the grid barrier. No atomics.
// -------------------------------------------------------------------------
__global__ __launch_bounds__(256, 2) void distance_kernel(
    const float* __restrict__ zx, const float* __restrict__ zy,
    float* __restrict__ ws)
{
    __shared__ __align__(16) _Float16 xs[64 * 128];   // 16 KB
    __shared__ __align__(16) _Float16 ys[32 * 128];   // 8 KB
    __shared__ float cpm[32][32], cpl[32][32];        // 8 KB

    float* stile = ws + WS_STILE;
    float* rowp  = ws + WS_ROWP;
    float* colp  = ws + WS_COLP;

    const int t    = threadIdx.x;
    const int tile = blockIdx.x >> 1;
    const int h    = blockIdx.x & 1;     // column half
    const int bx   = tile & 15;
    const int by   = tile >> 4;
    const int x0   = by * 64;
    const int y0   = bx * 64 + h * 32;

    // ---- stage x: 64 rows x 16 chunks (4/thread); y: 32 rows (2/thread) ----
    #pragma unroll
    for (int k = 0; k < 4; ++k) {
        int idx = t + k * 256;
        int r   = idx >> 4;
        int j   = idx & 15;
        int off = r * 128 + 8 * (j ^ ((r >> 2) & 7));
        const float4* gx = (const float4*)(zx + (size_t)(x0 + r) * DC + 8 * j);
        float4 v0 = gx[0], v1 = gx[1];
        uint4 hx;
        {
            H2U a, b, c, d;
            a.h.x = (_Float16)v0.x; a.h.y = (_Float16)v0.y;
            b.h.x = (_Float16)v0.z; b.h.y = (_Float16)v0.w;
            c.h.x = (_Float16)v1.x; c.h.y = (_Float16)v1.y;
            d.h.x = (_Float16)v1.z; d.h.y = (_Float16)v1.w;
            hx.x = a.u; hx.y = b.u; hx.z = c.u; hx.w = d.u;
        }
        *(uint4*)(xs + off) = hx;
    }
    #pragma unroll
    for (int k = 0; k < 2; ++k) {
        int idx = t + k * 256;
        int r   = idx >> 4;               // 0..31
        int j   = idx & 15;
        int off = r * 128 + 8 * (j ^ ((r >> 2) & 7));
        const float4* gy = (const float4*)(zy + (size_t)(y0 + r) * DC + 8 * j);
        float4 v0 = gy[0], v1 = gy[1];
        uint4 hy;
        {
            H2U a, b, c, d;
            a.h.x = (_Float16)v0.x; a.h.y = (_Float16)v0.y;
            b.h.x = (_Float16)v0.z; b.h.y = (_Float16)v0.w;
            c.h.x = (_Float16)v1.x; c.h.y = (_Float16)v1.y;
            d.h.x = (_Float16)v1.z; d.h.y = (_Float16)v1.w;
            hy.x = a.u; hy.y = b.u; hy.z = c.u; hy.w = d.u;
        }
        *(uint4*)(ys + off) = hy;
    }
    __syncthreads();

    const int tx = t & 7;             // 4 cols each (32 cols)
    const int ty = t >> 3;            // 0..31, 2 rows each (64 rows)
    const int xswz = (ty >> 1) & 7;   // == ((2ty+i)>>2)&7 for i in {0,1}
    const int yswz = tx;              // == ((4tx+q)>>2)&7 for q in {0..3}

    const _Float16* xb = xs + (2 * ty) * 128;
    const _Float16* yb = ys + (4 * tx) * 128;

    // ---- 2x4 micro-tile L1 distances, rolling prefetch ----
    float acc[2][4];
    #pragma unroll
    for (int i = 0; i < 2; ++i)
        #pragma unroll
        for (int j = 0; j < 4; ++j) acc[i][j] = 0.f;

    uint4 xc0 = *(const uint4*)(xb +       8 * (0 ^ xswz));
    uint4 xc1 = *(const uint4*)(xb + 128 + 8 * (0 ^ xswz));
    uint4 yc0 = *(const uint4*)(yb +       8 * (0 ^ yswz));
    uint4 yc1 = *(const uint4*)(yb + 128 + 8 * (0 ^ yswz));
    uint4 yc2 = *(const uint4*)(yb + 256 + 8 * (0 ^ yswz));
    uint4 yc3 = *(const uint4*)(yb + 384 + 8 * (0 ^ yswz));

    #pragma unroll 4
    for (int j = 0; j < 16; ++j) {
        uint4 xa0 = xc0, xa1 = xc1, ya0 = yc0, ya1 = yc1, ya2 = yc2, ya3 = yc3;
        const int jn = (j + 1) & 15;
        xc0 = *(const uint4*)(xb +       8 * (jn ^ xswz));
        xc1 = *(const uint4*)(xb + 128 + 8 * (jn ^ xswz));
        yc0 = *(const uint4*)(yb +       8 * (jn ^ yswz));
        yc1 = *(const uint4*)(yb + 128 + 8 * (jn ^ yswz));
        yc2 = *(const uint4*)(yb + 256 + 8 * (jn ^ yswz));
        yc3 = *(const uint4*)(yb + 384 + 8 * (jn ^ yswz));

        acc[0][0] = absdiff_dot(xa0, ya0, acc[0][0]);
        acc[0][1] = absdiff_dot(xa0, ya1, acc[0][1]);
        acc[0][2] = absdiff_dot(xa0, ya2, acc[0][2]);
        acc[0][3] = absdiff_dot(xa0, ya3, acc[0][3]);
        acc[1][0] = absdiff_dot(xa1, ya0, acc[1][0]);
        acc[1][1] = absdiff_dot(xa1, ya1, acc[1][1]);
        acc[1][2] = absdiff_dot(xa1, ya2, acc[1][2]);
        acc[1][3] = absdiff_dot(xa1, ya3, acc[1][3]);
    }

    float sv[2][4];
    #pragma unroll
    for (int i = 0; i < 2; ++i)
        #pragma unroll
        for (int j = 0; j < 4; ++j) sv[i][j] = -acc[i][j];

    // ---- store s half-tile (thread-contiguous; B reads with t = h*256+t') ----
    {
        float* sb = stile + (size_t)tile * 4096 + h * 2048 + t * 8;
        *(float4*)(sb)     = make_float4(sv[0][0], sv[0][1], sv[0][2], sv[0][3]);
        *(float4*)(sb + 4) = make_float4(sv[1][0], sv[1][1], sv[1][2], sv[1][3]);
    }

    // ---- per-half-tile ROW partials (merge across tx: lanes xor 1,2,4) ----
    #pragma unroll
    for (int i = 0; i < 2; ++i) {
        float m = fmaxf(fmaxf(sv[i][0], sv[i][1]), fmaxf(sv[i][2], sv[i][3]));
        float l = __expf(sv[i][0] - m) + __expf(sv[i][1] - m)
                + __expf(sv[i][2] - m) + __expf(sv[i][3] - m);
        #pragma unroll
        for (int off = 1; off < 8; off <<= 1) {
            float mo = __shfl_xor(m, off, 64);
            float lo = __shfl_xor(l, off, 64);
            float nm = fmaxf(m, mo);
            l = l * __expf(m - nm) + lo * __expf(mo - nm);
            m = nm;
        }
        if (tx == 0)
            *(float2*)(rowp + 2 * ((size_t)(x0 + 2 * ty + i) * 32 + bx * 2 + h)) = make_float2(m, l);
    }

    // ---- per-tile COL partials (this block owns its 32 cols fully) ----
    #pragma unroll
    for (int j = 0; j < 4; ++j) {
        float m = fmaxf(sv[0][j], sv[1][j]);
        float l = __expf(sv[0][j] - m) + __expf(sv[1][j] - m);
        cpm[ty][4 * tx + j] = m;
        cpl[ty][4 * tx + j] = l;
    }
    __syncthreads();
    if (t < 32) {
        float m = cpm[0][t], l = cpl[0][t];
        #pragma unroll 8
        for (int k = 1; k < 32; ++k) {
            float mo = cpm[k][t], lo = cpl[k][t];
            float nm = fmaxf(m, mo);
            l = l * __expf(m - nm) + lo * __expf(mo - nm);
            m = nm;
        }
        *(float2*)(colp + 2 * ((size_t)(y0 + t) * 16 + by)) = make_float2(m, l);
    }
}

// -------------------------------------------------------------------------
// Kernel B: 256 blocks (one per 64x64 tile) x 512 threads. Combine the 32
// row / 16 col partials per line (8 lanes/line, float4 loads + 3 shuffle
// merges), reload the s-tile, accumulate S0/S1, one float2 partial per tile.
// -------------------------------------------------------------------------
__global__ __launch_bounds__(512, 2) void reduce_kernel(
    const float* __restrict__ ws_in, float* __restrict__ ws_out)
{
    __shared__ float rm_s[64], rl_s[64], cm_s[64], cl_s[64];
    __shared__ float red0[8], red1[8];

    const float* stile = ws_in + WS_STILE;
    const float4* rowp4 = (const float4*)(ws_in + WS_ROWP);  // [row][16] of (m0,l0,m1,l1)
    const float4* colp4 = (const float4*)(ws_in + WS_COLP);  // [col][8]
    float* part = ws_out + WS_PART;

    const int t    = threadIdx.x;
    const int tile = blockIdx.x;
    const int bx   = tile & 15;
    const int by   = tile >> 4;
    const int x0   = by * 64;
    const int y0   = bx * 64;

    // prefetch s-tile (same linear layout kernel A wrote: t = h*256 + t')
    const float* sb = stile + (size_t)tile * 4096 + t * 8;
    float4 s0 = ((const float4*)sb)[0];
    float4 s1 = ((const float4*)sb)[1];

    const int item  = t >> 3;        // 0..63 (row or col index within tile)
    const int lane8 = t & 7;

    // ---- rows: 32 partials = 16 float4; 8 lanes x 2 float4 + 3 shuffles ----
    {
        float4 q0 = rowp4[(size_t)(x0 + item) * 16 + 2 * lane8];
        float4 q1 = rowp4[(size_t)(x0 + item) * 16 + 2 * lane8 + 1];
        float m = fmaxf(q0.x, q0.z);
        float l = q0.y * __expf(q0.x - m) + q0.w * __expf(q0.z - m);
        float m2 = fmaxf(q1.x, q1.z);
        float l2 = q1.y * __expf(q1.x - m2) + q1.w * __expf(q1.z - m2);
        float nm = fmaxf(m, m2);
        l = l * __expf(m - nm) + l2 * __expf(m2 - nm);
        m = nm;
        #pragma unroll
        for (int off = 1; off < 8; off <<= 1) {
            float mo = __shfl_xor(m, off, 64);
            float lo = __shfl_xor(l, off, 64);
            nm = fmaxf(m, mo);
            l = l * __expf(m - nm) + lo * __expf(mo - nm);
            m = nm;
        }
        if (lane8 == 0) { rm_s[item] = m; rl_s[item] = 1.f / l; }
    }
    // ---- cols: 16 partials = 8 float4; 8 lanes x 1 float4 + 3 shuffles ----
    {
        float4 q = colp4[(size_t)(y0 + item) * 8 + lane8];
        float m = fmaxf(q.x, q.z);
        float l = q.y * __expf(q.x - m) + q.w * __expf(q.z - m);
        #pragma unroll
        for (int off = 1; off < 8; off <<= 1) {
            float mo = __shfl_xor(m, off, 64);
            float lo = __shfl_xor(l, off, 64);
            float nm = fmaxf(m, mo);
            l = l * __expf(m - nm) + lo * __expf(mo - nm);
            m = nm;
        }
        if (lane8 == 0) { cm_s[item] = m; cl_s[item] = 1.f / l; }
    }
    __syncthreads();

    // thread t holds rows i0,i0+1 x cols c0..c0+3 per kernel A's layout
    const int tp = t & 255;
    const int hh = t >> 8;
    const int i0 = 2 * (tp >> 3);
    const int c0 = 32 * hh + 4 * (tp & 7);

    float sv[2][4] = {{s0.x, s0.y, s0.z, s0.w}, {s1.x, s1.y, s1.z, s1.w}};

    float S0 = 0.f, S1 = 0.f;
    #pragma unroll
    for (int i = 0; i < 2; ++i) {
        const float rm = rm_s[i0 + i];
        const float rl = rl_s[i0 + i];
        #pragma unroll
        for (int j = 0; j < 4; ++j) {
            const float cm = cm_s[c0 + j];
            const float cl = cl_s[c0 + j];
            float s = sv[i][j];
            float a = __expf(s - rm) * rl;
            float b = __expf(s - cm) * cl;
            float w = a + b - a * b;
            S0 += w;
            S1 += w * s;
        }
    }
    #pragma unroll
    for (int off = 32; off; off >>= 1) {
        S0 += __shfl_xor(S0, off, 64);
        S1 += __shfl_xor(S1, off, 64);
    }
    {
        const int wave = t >> 6, lane = t & 63;
        if (lane == 0) { red0[wave] = S0; red1[wave] = S1; }
    }
    __syncthreads();
    if (t == 0) {
        float t0 = 0.f, t1 = 0.f;
        #pragma unroll
        for (int w = 0; w < 8; ++w) { t0 += red0[w]; t1 += red1[w]; }
        *(float2*)(part + 2 * tile) = make_float2(t0, t1);
    }
}

// -------------------------------------------------------------------------
// Kernel C: sum 256 tile partials, write the 4 logits.
// -------------------------------------------------------------------------
__global__ __launch_bounds__(256) void finalize_kernel(
    const float* __restrict__ ws,
    const float* __restrict__ theta, const float* __restrict__ beta,
    float* __restrict__ out)
{
    __shared__ float red0[4], red1[4];
    const float* part = ws + WS_PART;
    const int t = threadIdx.x;

    float2 p = ((const float2*)part)[t];
    float S0 = p.x, S1 = p.y;
    #pragma unroll
    for (int off = 32; off; off >>= 1) {
        S0 += __shfl_xor(S0, off, 64);
        S1 += __shfl_xor(S1, off, 64);
    }
    const int wave = t >> 6, lane = t & 63;
    if (lane == 0) { red0[wave] = S0; red1[wave] = S1; }
    __syncthreads();
    if (t < NCM1) {
        float t0 = red0[0] + red0[1] + red0[2] + red0[3];
        float t1 = red1[0] + red1[1] + red1[2] + red1[3];
        float c = t1 / t0;
        out[t] = c * theta[t] + beta[t];
    }
}

// -------------------------------------------------------------------------
extern "C" void kernel_launch(void* const* d_in, const int* in_sizes, int n_in,
                              void* d_out, int out_size, void* d_ws, size_t ws_size,
                              hipStream_t stream)
{
    const float* zx    = (const float*)d_in[0];
    const float* zy    = (const float*)d_in[1];
    const float* theta = (const float*)d_in[2];
    const float* beta  = (const float*)d_in[3];
    float* out = (float*)d_out;
    float* ws  = (float*)d_ws;

    distance_kernel<<<NBLKA, 256, 0, stream>>>(zx, zy, ws);
    reduce_kernel<<<NTILE, 512, 0, stream>>>(ws, ws);
    finalize_kernel<<<1, 256, 0, stream>>>(ws, theta, beta, out);
}

// Round 9
// 74.362 us; speedup vs baseline: 1.0961x; 1.0310x over previous
//
#include <hip/hip_runtime.h>
#include <math.h>

// Problem constants (match reference)
#define NXC 1024
#define NYC 1024
#define DC  128
#define NCM1 4
#define NTILE 256   // 16x16 tiles of 64x64
#define NBLKA 512   // kernel A: 2 blocks per tile (64x32 half-tiles)

// ws float offsets
#define WS_STILE 0          // 1024*1024 fp16 s values = 524288 floats (2 MB)
#define WS_ROWP  524288     // float2[1024][32] (m,l) row partials -> 65536 floats
#define WS_COLP  589824     // float2[1024][16] (m,l) col partials -> 32768 floats
#define WS_PART  622592     // float2[256] (S0,S1) tile partials   ->   512 floats

typedef _Float16 half2v __attribute__((ext_vector_type(2)));
union H2U { half2v h; unsigned u; };

#if defined(__has_builtin)
#if __has_builtin(__builtin_amdgcn_fdot2)
#define HAVE_FDOT2 1
#endif
#endif

// |xa - ya| summed into f32 acc, 8 halves (one 16B chunk) at a time.
__device__ __forceinline__ float absdiff_dot(uint4 xa, uint4 ya, float acc)
{
    const unsigned* xu = (const unsigned*)&xa;
    const unsigned* yu = (const unsigned*)&ya;
    half2v one; one.x = (_Float16)1.f; one.y = (_Float16)1.f;
    #pragma unroll
    for (int q = 0; q < 4; ++q) {
        H2U x, y, d;
        x.u = xu[q]; y.u = yu[q];
        d.h = x.h - y.h;              // v_pk_add_f16 (neg)
        d.u &= 0x7FFF7FFFu;           // packed abs
#ifdef HAVE_FDOT2
        acc = __builtin_amdgcn_fdot2(d.h, one, acc, false);  // v_dot2_f32_f16
#else
        acc += (float)d.h.x + (float)d.h.y;
#endif
    }
    return acc;
}

// -------------------------------------------------------------------------
// Kernel A: 512 blocks x 256 threads, 2 blocks/CU. Block = 64x32 half-tile.
// fp16 staged LDS. Outputs: s half-tile as fp16 (one uint4/thread),
// per-half-tile row partials (32/row), per-tile col partials (16/col).
// Plain stores only; the kernel boundary is the grid barrier. No atomics.
// -------------------------------------------------------------------------
__global__ __launch_bounds__(256, 2) void distance_kernel(
    const float* __restrict__ zx, const float* __restrict__ zy,
    float* __restrict__ ws)
{
    __shared__ __align__(16) _Float16 xs[64 * 128];   // 16 KB
    __shared__ __align__(16) _Float16 ys[32 * 128];   // 8 KB
    __shared__ float cpm[32][32], cpl[32][32];        // 8 KB

    _Float16* stile = (_Float16*)(ws + WS_STILE);
    float* rowp  = ws + WS_ROWP;
    float* colp  = ws + WS_COLP;

    const int t    = threadIdx.x;
    const int tile = blockIdx.x >> 1;
    const int h    = blockIdx.x & 1;     // column half
    const int bx   = tile & 15;
    const int by   = tile >> 4;
    const int x0   = by * 64;
    const int y0   = bx * 64 + h * 32;

    // ---- stage x: 64 rows x 16 chunks (4/thread); y: 32 rows (2/thread) ----
    #pragma unroll
    for (int k = 0; k < 4; ++k) {
        int idx = t + k * 256;
        int r   = idx >> 4;
        int j   = idx & 15;
        int off = r * 128 + 8 * (j ^ ((r >> 2) & 7));
        const float4* gx = (const float4*)(zx + (size_t)(x0 + r) * DC + 8 * j);
        float4 v0 = gx[0], v1 = gx[1];
        uint4 hx;
        {
            H2U a, b, c, d;
            a.h.x = (_Float16)v0.x; a.h.y = (_Float16)v0.y;
            b.h.x = (_Float16)v0.z; b.h.y = (_Float16)v0.w;
            c.h.x = (_Float16)v1.x; c.h.y = (_Float16)v1.y;
            d.h.x = (_Float16)v1.z; d.h.y = (_Float16)v1.w;
            hx.x = a.u; hx.y = b.u; hx.z = c.u; hx.w = d.u;
        }
        *(uint4*)(xs + off) = hx;
    }
    #pragma unroll
    for (int k = 0; k < 2; ++k) {
        int idx = t + k * 256;
        int r   = idx >> 4;               // 0..31
        int j   = idx & 15;
        int off = r * 128 + 8 * (j ^ ((r >> 2) & 7));
        const float4* gy = (const float4*)(zy + (size_t)(y0 + r) * DC + 8 * j);
        float4 v0 = gy[0], v1 = gy[1];
        uint4 hy;
        {
            H2U a, b, c, d;
            a.h.x = (_Float16)v0.x; a.h.y = (_Float16)v0.y;
            b.h.x = (_Float16)v0.z; b.h.y = (_Float16)v0.w;
            c.h.x = (_Float16)v1.x; c.h.y = (_Float16)v1.y;
            d.h.x = (_Float16)v1.z; d.h.y = (_Float16)v1.w;
            hy.x = a.u; hy.y = b.u; hy.z = c.u; hy.w = d.u;
        }
        *(uint4*)(ys + off) = hy;
    }
    __syncthreads();

    const int tx = t & 7;             // 4 cols each (32 cols)
    const int ty = t >> 3;            // 0..31, 2 rows each (64 rows)
    const int xswz = (ty >> 1) & 7;
    const int yswz = tx;

    const _Float16* xb = xs + (2 * ty) * 128;
    const _Float16* yb = ys + (4 * tx) * 128;

    // ---- 2x4 micro-tile L1 distances, rolling prefetch ----
    float acc[2][4];
    #pragma unroll
    for (int i = 0; i < 2; ++i)
        #pragma unroll
        for (int j = 0; j < 4; ++j) acc[i][j] = 0.f;

    uint4 xc0 = *(const uint4*)(xb +       8 * (0 ^ xswz));
    uint4 xc1 = *(const uint4*)(xb + 128 + 8 * (0 ^ xswz));
    uint4 yc0 = *(const uint4*)(yb +       8 * (0 ^ yswz));
    uint4 yc1 = *(const uint4*)(yb + 128 + 8 * (0 ^ yswz));
    uint4 yc2 = *(const uint4*)(yb + 256 + 8 * (0 ^ yswz));
    uint4 yc3 = *(const uint4*)(yb + 384 + 8 * (0 ^ yswz));

    #pragma unroll 4
    for (int j = 0; j < 16; ++j) {
        uint4 xa0 = xc0, xa1 = xc1, ya0 = yc0, ya1 = yc1, ya2 = yc2, ya3 = yc3;
        const int jn = (j + 1) & 15;
        xc0 = *(const uint4*)(xb +       8 * (jn ^ xswz));
        xc1 = *(const uint4*)(xb + 128 + 8 * (jn ^ xswz));
        yc0 = *(const uint4*)(yb +       8 * (jn ^ yswz));
        yc1 = *(const uint4*)(yb + 128 + 8 * (jn ^ yswz));
        yc2 = *(const uint4*)(yb + 256 + 8 * (jn ^ yswz));
        yc3 = *(const uint4*)(yb + 384 + 8 * (jn ^ yswz));

        acc[0][0] = absdiff_dot(xa0, ya0, acc[0][0]);
        acc[0][1] = absdiff_dot(xa0, ya1, acc[0][1]);
        acc[0][2] = absdiff_dot(xa0, ya2, acc[0][2]);
        acc[0][3] = absdiff_dot(xa0, ya3, acc[0][3]);
        acc[1][0] = absdiff_dot(xa1, ya0, acc[1][0]);
        acc[1][1] = absdiff_dot(xa1, ya1, acc[1][1]);
        acc[1][2] = absdiff_dot(xa1, ya2, acc[1][2]);
        acc[1][3] = absdiff_dot(xa1, ya3, acc[1][3]);
    }

    float sv[2][4];
    #pragma unroll
    for (int i = 0; i < 2; ++i)
        #pragma unroll
        for (int j = 0; j < 4; ++j) sv[i][j] = -acc[i][j];

    // ---- store s half-tile as fp16 (one uint4 per thread) ----
    {
        H2U p0, p1, p2, p3;
        p0.h.x = (_Float16)sv[0][0]; p0.h.y = (_Float16)sv[0][1];
        p1.h.x = (_Float16)sv[0][2]; p1.h.y = (_Float16)sv[0][3];
        p2.h.x = (_Float16)sv[1][0]; p2.h.y = (_Float16)sv[1][1];
        p3.h.x = (_Float16)sv[1][2]; p3.h.y = (_Float16)sv[1][3];
        uint4 pk; pk.x = p0.u; pk.y = p1.u; pk.z = p2.u; pk.w = p3.u;
        *(uint4*)(stile + (size_t)tile * 4096 + h * 2048 + t * 8) = pk;
    }

    // ---- per-half-tile ROW partials (merge across tx: lanes xor 1,2,4) ----
    #pragma unroll
    for (int i = 0; i < 2; ++i) {
        float m = fmaxf(fmaxf(sv[i][0], sv[i][1]), fmaxf(sv[i][2], sv[i][3]));
        float l = __expf(sv[i][0] - m) + __expf(sv[i][1] - m)
                + __expf(sv[i][2] - m) + __expf(sv[i][3] - m);
        #pragma unroll
        for (int off = 1; off < 8; off <<= 1) {
            float mo = __shfl_xor(m, off, 64);
            float lo = __shfl_xor(l, off, 64);
            float nm = fmaxf(m, mo);
            l = l * __expf(m - nm) + lo * __expf(mo - nm);
            m = nm;
        }
        if (tx == 0)
            *(float2*)(rowp + 2 * ((size_t)(x0 + 2 * ty + i) * 32 + bx * 2 + h)) = make_float2(m, l);
    }

    // ---- per-tile COL partials (this block owns its 32 cols fully) ----
    #pragma unroll
    for (int j = 0; j < 4; ++j) {
        float m = fmaxf(sv[0][j], sv[1][j]);
        float l = __expf(sv[0][j] - m) + __expf(sv[1][j] - m);
        cpm[ty][4 * tx + j] = m;
        cpl[ty][4 * tx + j] = l;
    }
    __syncthreads();
    if (t < 32) {
        float m = cpm[0][t], l = cpl[0][t];
        #pragma unroll 8
        for (int k = 1; k < 32; ++k) {
            float mo = cpm[k][t], lo = cpl[k][t];
            float nm = fmaxf(m, mo);
            l = l * __expf(m - nm) + lo * __expf(mo - nm);
            m = nm;
        }
        *(float2*)(colp + 2 * ((size_t)(y0 + t) * 16 + by)) = make_float2(m, l);
    }
}

// -------------------------------------------------------------------------
// Kernel B: 256 blocks (one per 64x64 tile) x 512 threads. Combine the 32
// row / 16 col partials per line (8 lanes/line, float4 loads + 3 shuffle
// merges), reload the fp16 s-tile (one uint4/thread, prefetched),
// accumulate S0/S1, one float2 partial per tile.
// -------------------------------------------------------------------------
__global__ __launch_bounds__(512, 2) void reduce_kernel(
    const float* __restrict__ ws_in, float* __restrict__ ws_out)
{
    __shared__ float rm_s[64], rl_s[64], cm_s[64], cl_s[64];
    __shared__ float red0[8], red1[8];

    const _Float16* stile = (const _Float16*)(ws_in + WS_STILE);
    const float4* rowp4 = (const float4*)(ws_in + WS_ROWP);  // [row][16] of (m0,l0,m1,l1)
    const float4* colp4 = (const float4*)(ws_in + WS_COLP);  // [col][8]
    float* part = ws_out + WS_PART;

    const int t    = threadIdx.x;
    const int tile = blockIdx.x;
    const int bx   = tile & 15;
    const int by   = tile >> 4;
    const int x0   = by * 64;
    const int y0   = bx * 64;

    // prefetch fp16 s-tile chunk (same linear layout A wrote: t = h*256 + t')
    uint4 pk = *(const uint4*)(stile + (size_t)tile * 4096 + t * 8);

    const int item  = t >> 3;        // 0..63 (row or col index within tile)
    const int lane8 = t & 7;

    // ---- rows: 32 partials = 16 float4; 8 lanes x 2 float4 + 3 shuffles ----
    {
        float4 q0 = rowp4[(size_t)(x0 + item) * 16 + 2 * lane8];
        float4 q1 = rowp4[(size_t)(x0 + item) * 16 + 2 * lane8 + 1];
        float m = fmaxf(q0.x, q0.z);
        float l = q0.y * __expf(q0.x - m) + q0.w * __expf(q0.z - m);
        float m2 = fmaxf(q1.x, q1.z);
        float l2 = q1.y * __expf(q1.x - m2) + q1.w * __expf(q1.z - m2);
        float nm = fmaxf(m, m2);
        l = l * __expf(m - nm) + l2 * __expf(m2 - nm);
        m = nm;
        #pragma unroll
        for (int off = 1; off < 8; off <<= 1) {
            float mo = __shfl_xor(m, off, 64);
            float lo = __shfl_xor(l, off, 64);
            nm = fmaxf(m, mo);
            l = l * __expf(m - nm) + lo * __expf(mo - nm);
            m = nm;
        }
        if (lane8 == 0) { rm_s[item] = m; rl_s[item] = 1.f / l; }
    }
    // ---- cols: 16 partials = 8 float4; 8 lanes x 1 float4 + 3 shuffles ----
    {
        float4 q = colp4[(size_t)(y0 + item) * 8 + lane8];
        float m = fmaxf(q.x, q.z);
        float l = q.y * __expf(q.x - m) + q.w * __expf(q.z - m);
        #pragma unroll
        for (int off = 1; off < 8; off <<= 1) {
            float mo = __shfl_xor(m, off, 64);
            float lo = __shfl_xor(l, off, 64);
            float nm = fmaxf(m, mo);
            l = l * __expf(m - nm) + lo * __expf(mo - nm);
            m = nm;
        }
        if (lane8 == 0) { cm_s[item] = m; cl_s[item] = 1.f / l; }
    }
    __syncthreads();

    // thread t holds rows i0,i0+1 x cols c0..c0+3 per kernel A's layout
    const int tp = t & 255;
    const int hh = t >> 8;
    const int i0 = 2 * (tp >> 3);
    const int c0 = 32 * hh + 4 * (tp & 7);

    // unpack fp16 s values
    float sv[2][4];
    {
        H2U u0, u1, u2, u3;
        u0.u = pk.x; u1.u = pk.y; u2.u = pk.z; u3.u = pk.w;
        sv[0][0] = (float)u0.h.x; sv[0][1] = (float)u0.h.y;
        sv[0][2] = (float)u1.h.x; sv[0][3] = (float)u1.h.y;
        sv[1][0] = (float)u2.h.x; sv[1][1] = (float)u2.h.y;
        sv[1][2] = (float)u3.h.x; sv[1][3] = (float)u3.h.y;
    }

    float S0 = 0.f, S1 = 0.f;
    #pragma unroll
    for (int i = 0; i < 2; ++i) {
        const float rm = rm_s[i0 + i];
        const float rl = rl_s[i0 + i];
        #pragma unroll
        for (int j = 0; j < 4; ++j) {
            const float cm = cm_s[c0 + j];
            const float cl = cl_s[c0 + j];
            float s = sv[i][j];
            float a = __expf(s - rm) * rl;
            float b = __expf(s - cm) * cl;
            float w = a + b - a * b;
            S0 += w;
            S1 += w * s;
        }
    }
    #pragma unroll
    for (int off = 32; off; off >>= 1) {
        S0 += __shfl_xor(S0, off, 64);
        S1 += __shfl_xor(S1, off, 64);
    }
    {
        const int wave = t >> 6, lane = t & 63;
        if (lane == 0) { red0[wave] = S0; red1[wave] = S1; }
    }
    __syncthreads();
    if (t == 0) {
        float t0 = 0.f, t1 = 0.f;
        #pragma unroll
        for (int w = 0; w < 8; ++w) { t0 += red0[w]; t1 += red1[w]; }
        *(float2*)(part + 2 * tile) = make_float2(t0, t1);
    }
}

// -------------------------------------------------------------------------
// Kernel C: sum 256 tile partials, write the 4 logits.
// -------------------------------------------------------------------------
__global__ __launch_bounds__(256) void finalize_kernel(
    const float* __restrict__ ws,
    const float* __restrict__ theta, const float* __restrict__ beta,
    float* __restrict__ out)
{
    __shared__ float red0[4], red1[4];
    const float* part = ws + WS_PART;
    const int t = threadIdx.x;

    float2 p = ((const float2*)part)[t];
    float S0 = p.x, S1 = p.y;
    #pragma unroll
    for (int off = 32; off; off >>= 1) {
        S0 += __shfl_xor(S0, off, 64);
        S1 += __shfl_xor(S1, off, 64);
    }
    const int wave = t >> 6, lane = t & 63;
    if (lane == 0) { red0[wave] = S0; red1[wave] = S1; }
    __syncthreads();
    if (t < NCM1) {
        float t0 = red0[0] + red0[1] + red0[2] + red0[3];
        float t1 = red1[0] + red1[1] + red1[2] + red1[3];
        float c = t1 / t0;
        out[t] = c * theta[t] + beta[t];
    }
}

// -------------------------------------------------------------------------
extern "C" void kernel_launch(void* const* d_in, const int* in_sizes, int n_in,
                              void* d_out, int out_size, void* d_ws, size_t ws_size,
                              hipStream_t stream)
{
    const float* zx    = (const float*)d_in[0];
    const float* zy    = (const float*)d_in[1];
    const float* theta = (const float*)d_in[2];
    const float* beta  = (const float*)d_in[3];
    float* out = (float*)d_out;
    float* ws  = (float*)d_ws;

    distance_kernel<<<NBLKA, 256, 0, stream>>>(zx, zy, ws);
    reduce_kernel<<<NTILE, 512, 0, stream>>>(ws, ws);
    finalize_kernel<<<1, 256, 0, stream>>>(ws, theta, beta, out);
}